// Round 1
// 86.605 us; speedup vs baseline: 1.0570x; 1.0570x over previous
//
#include <hip/hip_runtime.h>

#define ND 512   // directions
#define NP 64    // points per ray
#define NR 32    // rank
#define NF 256   // virtual subcarriers
#define RSTRIDE 56  // ushorts per LDS row (112 B: 16B-aligned, 2-way banks only)

typedef __attribute__((ext_vector_type(8))) short bf16x8;   // 8 bf16 = 4 VGPRs
typedef __attribute__((ext_vector_type(4))) float f32x4;

// float -> bf16 (RNE); inputs are finite.
__device__ inline unsigned short f2bf(float x) {
    unsigned u = __builtin_bit_cast(unsigned, x);
    u += 0x7FFFu + ((u >> 16) & 1u);
    return (unsigned short)(u >> 16);
}
__device__ inline unsigned pack2(float a, float b) {
    return (unsigned)f2bf(a) | ((unsigned)f2bf(b) << 16);
}

// One block per direction d; 256 threads = 4 waves; wave wv owns n-tiles
// 4wv..4wv+3 (64 freqs). M rows = points p (0..63). All three complex
// projections use the SAME conj pattern via chained MFMAs:
//   re = mfma(x_i, vi, mfma(x_r, vr, 0))      = sum x_r*vr + x_i*vi
//   im = mfma(x_i, -vr, mfma(x_r, vi, 0))     = sum x_r*vi - x_i*vr
// cumsum's im plane is stored NEGATED in LDS so its plain (non-conj)
// projection is expressed by the conj pattern. The cumsum row p=0 is
// zeroed so the second-order term's p>=1 restriction is automatic.
//
// Epilogue: NO atomics. Each block writes its scaled 512-float partial
// vector (256 re + 256 im) to ws[d*512 ..]; a second tiny kernel reduces
// over d and writes out. This removes (a) the hipMemsetAsync graph node
// and (b) the 512-deep serialized atomicAdd chain per output address.
__global__ __launch_bounds__(256, 2) void lrrt_mfma3_kernel(
    const float* __restrict__ att_re, const float* __restrict__ att_im,
    const float* __restrict__ rad_re, const float* __restrict__ rad_im,
    const float* __restrict__ freq_re, const float* __restrict__ freq_im,
    const int* __restrict__ mrl, float* __restrict__ ws)
{
    // 0=att_re 1=att_im 2=rad_re 3=rad_im 4=cum_re 5=-cum_im : 42 KB
    __shared__ __align__(16) unsigned short s_mat[6][NP * RSTRIDE];
    __shared__ float s_segtot[256];  // per-(seg,reim,r) segment totals

    const int t = threadIdx.x;
    const int d = blockIdx.x;
    const size_t base = (size_t)d * (NP * NR);
    const int lane = t & 63;
    const int wv = t >> 6;
    const int kg = lane >> 4;       // k-group: rank cols 8kg..8kg+7; rows kg*4..+3
    const int m_lo = lane & 15;

    // --- 1a. stage att/rad as bf16 into padded LDS (no pointer arrays) ---
#pragma unroll
    for (int half = 0; half < 2; ++half) {
        const int w = t + half * 256;        // float4 index 0..511
        const int p = w >> 3;
        const int c = (w & 7) * 4;
        const size_t g = base + (size_t)p * NR + c;
        const int lo = p * RSTRIDE + c;
        float4 x;
        x = *(const float4*)(att_re + g);
        *(uint2*)&s_mat[0][lo] = make_uint2(pack2(x.x, x.y), pack2(x.z, x.w));
        x = *(const float4*)(att_im + g);
        *(uint2*)&s_mat[1][lo] = make_uint2(pack2(x.x, x.y), pack2(x.z, x.w));
        x = *(const float4*)(rad_re + g);
        *(uint2*)&s_mat[2][lo] = make_uint2(pack2(x.x, x.y), pack2(x.z, x.w));
        x = *(const float4*)(rad_im + g);
        *(uint2*)&s_mat[3][lo] = make_uint2(pack2(x.x, x.y), pack2(x.z, x.w));
    }

    // --- 1b. segmented cumsum of att along p (4 segs x 16 points) ---
    // t = seg*64 + reim*32 + r
    const int cs_r = t & 31;
    const int cs_reim = (t >> 5) & 1;
    const int cs_seg = t >> 6;
    float vals[16];
    {
        const float* src = cs_reim ? att_im : att_re;
        float run = 0.f;
#pragma unroll
        for (int i = 0; i < 16; ++i) {
            run += src[base + (cs_seg * 16 + i) * NR + cs_r];
            vals[i] = run;
        }
        s_segtot[t] = run;
    }
    __syncthreads();  // staged att/rad + segment totals visible

    // --- 1c. add segment offsets; store cum_re / -cum_im bf16; zero p=0 row ---
    {
        float off = 0.f;
#pragma unroll
        for (int s = 0; s < 3; ++s)
            if (s < cs_seg) off += s_segtot[s * 64 + cs_reim * 32 + cs_r];
        const float sgn = cs_reim ? -1.f : 1.f;
        unsigned short* dst = s_mat[4 + cs_reim];
#pragma unroll
        for (int i = 0; i < 16; ++i) {
            const int p = cs_seg * 16 + i;
            dst[p * RSTRIDE + cs_r] = (p == 0) ? (unsigned short)0
                                               : f2bf(sgn * (vals[i] + off));
        }
    }
    __syncthreads();  // cumsum visible

    // --- 2. B fragments into registers: vr, vi, and -vr per n-tile ---
    bf16x8 bvr[4], bvi[4], bvn[4];
#pragma unroll
    for (int q = 0; q < 4; ++q) {
        const int n = 16 * (4 * wv + q) + m_lo;
        const float4* fre = (const float4*)(freq_re + (size_t)n * NR + 8 * kg);
        const float4* fim = (const float4*)(freq_im + (size_t)n * NR + 8 * kg);
        const float4 r0 = fre[0], r1 = fre[1];
        const float4 i0 = fim[0], i1 = fim[1];
        bf16x8 vr, vi, vn;
        vr[0] = f2bf(r0.x); vr[1] = f2bf(r0.y); vr[2] = f2bf(r0.z); vr[3] = f2bf(r0.w);
        vr[4] = f2bf(r1.x); vr[5] = f2bf(r1.y); vr[6] = f2bf(r1.z); vr[7] = f2bf(r1.w);
        vi[0] = f2bf(i0.x); vi[1] = f2bf(i0.y); vi[2] = f2bf(i0.z); vi[3] = f2bf(i0.w);
        vi[4] = f2bf(i1.x); vi[5] = f2bf(i1.y); vi[6] = f2bf(i1.z); vi[7] = f2bf(i1.w);
        vn[0] = f2bf(-r0.x); vn[1] = f2bf(-r0.y); vn[2] = f2bf(-r0.z); vn[3] = f2bf(-r0.w);
        vn[4] = f2bf(-r1.x); vn[5] = f2bf(-r1.y); vn[6] = f2bf(-r1.z); vn[7] = f2bf(-r1.w);
        bvr[q] = vr; bvi[q] = vi; bvn[q] = vn;
    }

    // --- 3. MFMA main loop: 4 m-tiles x 4 n-tiles x 6 chained pairs ---
    const float delta_t = (float)(*mrl) / (float)NP;
    float pre[4] = {0.f, 0.f, 0.f, 0.f};
    float pim[4] = {0.f, 0.f, 0.f, 0.f};
    const f32x4 zero = {0.f, 0.f, 0.f, 0.f};

#pragma unroll 1
    for (int mt = 0; mt < 4; ++mt) {
        const int off = (mt * 16 + m_lo) * RSTRIDE + 8 * kg;
        const bf16x8 a_r = *(const bf16x8*)&s_mat[0][off];
        const bf16x8 a_i = *(const bf16x8*)&s_mat[1][off];
        const bf16x8 r_r = *(const bf16x8*)&s_mat[2][off];
        const bf16x8 r_i = *(const bf16x8*)&s_mat[3][off];
        const bf16x8 c_r = *(const bf16x8*)&s_mat[4][off];
        const bf16x8 c_i = *(const bf16x8*)&s_mat[5][off];
#pragma unroll
        for (int q = 0; q < 4; ++q) {
            f32x4 Are = __builtin_amdgcn_mfma_f32_16x16x32_bf16(a_r, bvr[q], zero, 0, 0, 0);
            f32x4 Aim = __builtin_amdgcn_mfma_f32_16x16x32_bf16(a_r, bvi[q], zero, 0, 0, 0);
            f32x4 Bre = __builtin_amdgcn_mfma_f32_16x16x32_bf16(r_r, bvr[q], zero, 0, 0, 0);
            f32x4 Bim = __builtin_amdgcn_mfma_f32_16x16x32_bf16(r_r, bvi[q], zero, 0, 0, 0);
            f32x4 Ure = __builtin_amdgcn_mfma_f32_16x16x32_bf16(c_r, bvr[q], zero, 0, 0, 0);
            f32x4 Uim = __builtin_amdgcn_mfma_f32_16x16x32_bf16(c_r, bvi[q], zero, 0, 0, 0);
            Are = __builtin_amdgcn_mfma_f32_16x16x32_bf16(a_i, bvi[q], Are, 0, 0, 0);
            Aim = __builtin_amdgcn_mfma_f32_16x16x32_bf16(a_i, bvn[q], Aim, 0, 0, 0);
            Bre = __builtin_amdgcn_mfma_f32_16x16x32_bf16(r_i, bvi[q], Bre, 0, 0, 0);
            Bim = __builtin_amdgcn_mfma_f32_16x16x32_bf16(r_i, bvn[q], Bim, 0, 0, 0);
            Ure = __builtin_amdgcn_mfma_f32_16x16x32_bf16(c_i, bvi[q], Ure, 0, 0, 0);
            Uim = __builtin_amdgcn_mfma_f32_16x16x32_bf16(c_i, bvn[q], Uim, 0, 0, 0);
#pragma unroll
            for (int i = 0; i < 4; ++i) {
                const float qre = Bre[i] * Are[i] - Bim[i] * Aim[i];
                const float qim = Bre[i] * Aim[i] + Bim[i] * Are[i];
                const float cre = fmaf(delta_t, Ure[i], 1.0f);  // 1 + dt*u_re
                const float cim = delta_t * Uim[i];             // dt*u_im
                pre[q] = fmaf(qre, cre, fmaf(-qim, cim, pre[q]));
                pim[q] = fmaf(qim, cre, fmaf(qre, cim, pim[q]));
            }
        }
    }

    // --- 4. reduce across row-groups (lanes ^16, ^32); store partials ---
    const float scale = delta_t / (float)ND;
    float* wsd = ws + (size_t)d * (2 * NF);   // 512 floats per direction
#pragma unroll
    for (int q = 0; q < 4; ++q) {
        float re = pre[q], im = pim[q];
        re += __shfl_xor(re, 16, 64); im += __shfl_xor(im, 16, 64);
        re += __shfl_xor(re, 32, 64); im += __shfl_xor(im, 32, 64);
        if (lane < 16) {
            const int f = 16 * (4 * wv + q) + lane;
            wsd[f] = re * scale;          // re partial
            wsd[NF + f] = im * scale;     // im partial
        }
    }
}

// Reduce ws[d][512] over d and write out[512] (overwrites poison; no memset).
// 8 blocks x 256 threads: block b owns outputs j in [64b, 64b+64); the 4
// thread-groups of 64 each sum a 128-direction slice (16 loads in flight),
// then an LDS reduce combines the 4 slices.
__global__ __launch_bounds__(256) void lrrt_reduce_kernel(
    const float* __restrict__ ws, float* __restrict__ out)
{
    __shared__ float red[256];
    const int jloc = threadIdx.x & 63;
    const int dg = threadIdx.x >> 6;             // 0..3
    const int j = blockIdx.x * 64 + jloc;        // 8 blocks -> j in [0,512)
    float s0 = 0.f, s1 = 0.f, s2 = 0.f, s3 = 0.f;
    const int d0 = dg * 128;
#pragma unroll 4
    for (int dd = 0; dd < 128; dd += 4) {
        s0 += ws[(size_t)(d0 + dd + 0) * (2 * NF) + j];
        s1 += ws[(size_t)(d0 + dd + 1) * (2 * NF) + j];
        s2 += ws[(size_t)(d0 + dd + 2) * (2 * NF) + j];
        s3 += ws[(size_t)(d0 + dd + 3) * (2 * NF) + j];
    }
    red[threadIdx.x] = (s0 + s1) + (s2 + s3);
    __syncthreads();
    if (dg == 0)
        out[j] = red[jloc] + red[64 + jloc] + red[128 + jloc] + red[192 + jloc];
}

extern "C" void kernel_launch(void* const* d_in, const int* in_sizes, int n_in,
                              void* d_out, int out_size, void* d_ws, size_t ws_size,
                              hipStream_t stream) {
    const float* att_re = (const float*)d_in[0];
    const float* att_im = (const float*)d_in[1];
    const float* rad_re = (const float*)d_in[2];
    const float* rad_im = (const float*)d_in[3];
    const float* freq_re = (const float*)d_in[4];
    const float* freq_im = (const float*)d_in[5];
    const int* mrl = (const int*)d_in[6];
    float* out = (float*)d_out;
    float* ws = (float*)d_ws;   // needs 512*512*4 B = 1 MiB; fully overwritten

    // No hipMemsetAsync: k1 overwrites its ws slots with plain stores,
    // k2 overwrites the poisoned d_out with plain stores.
    lrrt_mfma3_kernel<<<ND, 256, 0, stream>>>(
        att_re, att_im, rad_re, rad_im, freq_re, freq_im, mrl, ws);
    lrrt_reduce_kernel<<<8, 256, 0, stream>>>(ws, out);
}